// Round 1
// baseline (70.304 us; speedup 1.0000x reference)
//
#include <hip/hip_runtime.h>

// AdderVDSR collapses analytically:
//   adder_conv(h, w) = -sum|patch - w| < 0 everywhere (nonzero weights),
//   relu(negative) == 0 exactly  =>  h after the 16-block scan is identically 0.
//   out = conv3(0, out_w, out_b) + residual
//       = out_b[c] + pixel_shuffle(conv3(x, up_w, up_b), 2)
// Only the upsampler conv (3->12ch, 3x3, pad 1) + shuffle + biases remain.
//
// R3 structure: one thread per SOURCE pixel (b,c,h,w). The 2x2 output cell
// (4 output channels oc = c*4 + r1*2 + r2) shares one 27-element patch:
// 4x fewer global loads than one-thread-per-output. (b,c) is block-uniform,
// so weights/biases are uniform LDS broadcasts. Stores: 2x float2, coalesced.

#define BATCH 2
#define CIN   3
#define HS    128
#define WS    128
#define H2    256
#define W2    256

__global__ __launch_bounds__(256) void upshuffle4_kernel(
    const float* __restrict__ x,      // [2,3,128,128]
    const float* __restrict__ up_w,   // [12,3,3,3] = [c][oc4][ic][ky][kx] w/ oc=c*4+oc4
    const float* __restrict__ up_b,   // [12]
    const float* __restrict__ out_b,  // [3]
    float* __restrict__ out)          // [2,3,256,256]
{
    __shared__ float sw[4 * CIN * 9]; // 108 weights for this block's c group
    __shared__ float sb4[4];          // up_b for the 4 ocs
    __shared__ float sob;             // out_b[c]

    const int blocksPerPlane = (HS * WS) / 256;        // 64
    const int bc = blockIdx.x / blocksPerPlane;        // 0..5, block-uniform
    const int c  = bc % CIN;
    const int b  = bc / CIN;

    const int t = threadIdx.x;
    if (t < 108) sw[t]  = up_w[c * 108 + t];           // [oc4][ic][3][3]
    if (t < 4)   sb4[t] = up_b[c * 4 + t];
    if (t == 0)  sob    = out_b[c];
    __syncthreads();

    const int pix = (blockIdx.x % blocksPerPlane) * 256 + t;  // 0..16383
    const int w   = pix & (WS - 1);
    const int h   = pix >> 7;                          // WS == 128

    const float* __restrict__ xb = x + (size_t)(b * CIN) * HS * WS;

    // acc[r1*2+r2] for out[b,c,2h+r1,2w+r2]
    float a00 = sb4[0], a01 = sb4[1], a10 = sb4[2], a11 = sb4[3];

    #pragma unroll
    for (int ic = 0; ic < CIN; ++ic) {
        const float* __restrict__ xp = xb + ic * HS * WS;
        #pragma unroll
        for (int ky = 0; ky < 3; ++ky) {
            const int iy   = h + ky - 1;
            const bool yok = (unsigned)iy < (unsigned)HS;
            const float* __restrict__ row = xp + iy * WS + w;
            const float p0 = (yok && w > 0)      ? row[-1] : 0.0f;
            const float p1 =  yok                ? row[0]  : 0.0f;
            const float p2 = (yok && w < WS - 1) ? row[1]  : 0.0f;
            const float* __restrict__ wp = sw + ic * 9 + ky * 3;  // + oc4*27
            a00 = fmaf(p0, wp[0],      fmaf(p1, wp[1],      fmaf(p2, wp[2],      a00)));
            a01 = fmaf(p0, wp[27],     fmaf(p1, wp[28],     fmaf(p2, wp[29],     a01)));
            a10 = fmaf(p0, wp[54],     fmaf(p1, wp[55],     fmaf(p2, wp[56],     a10)));
            a11 = fmaf(p0, wp[81],     fmaf(p1, wp[82],     fmaf(p2, wp[83],     a11)));
        }
    }

    float2 r0 = make_float2(a00 + sob, a01 + sob);
    float2 r1 = make_float2(a10 + sob, a11 + sob);
    float* __restrict__ ob = out + (((size_t)(b * CIN + c) * H2) + 2 * h) * W2 + 2 * w;
    *(float2*)ob        = r0;
    *(float2*)(ob + W2) = r1;
}

extern "C" void kernel_launch(void* const* d_in, const int* in_sizes, int n_in,
                              void* d_out, int out_size, void* d_ws, size_t ws_size,
                              hipStream_t stream) {
    // setup_inputs order: x, up_w, up_b, in_w, in_b, adder_w, out_w, out_b
    const float* x     = (const float*)d_in[0];
    const float* up_w  = (const float*)d_in[1];
    const float* up_b  = (const float*)d_in[2];
    const float* out_b = (const float*)d_in[7];
    float* out = (float*)d_out;

    const int blocks = BATCH * CIN * (HS * WS) / 256;  // 384
    upshuffle4_kernel<<<blocks, 256, 0, stream>>>(x, up_w, up_b, out_b, out);
}

// Round 2
// 69.794 us; speedup vs baseline: 1.0073x; 1.0073x over previous
//
#include <hip/hip_runtime.h>

// AdderVDSR collapses analytically:
//   adder_conv(h, w) = -sum|patch - w| < 0 everywhere (nonzero weights),
//   relu(negative) == 0 exactly  =>  h after the 16-block scan is identically 0.
//   out = conv3(0, out_w, out_b) + residual
//       = out_b[c] + pixel_shuffle(conv3(x, up_w, up_b), 2)
// Only the upsampler conv (3->12ch, 3x3, pad 1) + shuffle + biases remain.
//
// R5 structure: one thread per PAIR of source pixels (h, w) and (h, w+1).
// The 4-float row segment x[w-1..w+2] feeding both pixels' patches is
// fetched as scalar + aligned float2 + scalar (3 loads per (ic,ky) for two
// pixels vs 6 in the 1-px/thread version). Each wave owns one source row,
// so the y-bounds check is wave-uniform (no divergence). Outputs for the
// pair are contiguous: two aligned float4 stores per thread, wave-coalesced.

#define BATCH 2
#define CIN   3
#define HS    128
#define WS    128
#define H2    256
#define W2    256

__global__ __launch_bounds__(256) void upshuffle4x2_kernel(
    const float* __restrict__ x,      // [2,3,128,128]
    const float* __restrict__ up_w,   // [12,3,3,3] = [c][oc4][ic][ky][kx], oc=c*4+oc4
    const float* __restrict__ up_b,   // [12]
    const float* __restrict__ out_b,  // [3]
    float* __restrict__ out)          // [2,3,256,256]
{
    __shared__ float sw[4 * CIN * 9]; // 108 weights for this block's c group
    __shared__ float sb4[4];          // up_b for the 4 ocs
    __shared__ float sob;             // out_b[c]

    const int blocksPerPlane = (HS * (WS / 2)) / 256;  // 32
    const int bc = blockIdx.x / blocksPerPlane;        // 0..5, block-uniform
    const int c  = bc % CIN;
    const int b  = bc / CIN;

    const int t = threadIdx.x;
    if (t < 108) sw[t]  = up_w[c * 108 + t];           // [oc4][ic][3][3]
    if (t < 4)   sb4[t] = up_b[c * 4 + t];
    if (t == 0)  sob    = out_b[c];
    __syncthreads();

    const int pairIdx = (blockIdx.x % blocksPerPlane) * 256 + t; // 0..8191
    const int w2 = pairIdx & 63;          // pair index within row
    const int h  = pairIdx >> 6;          // wave-uniform (64 pairs per row)
    const int w  = w2 * 2;

    const float* __restrict__ xb = x + (size_t)(b * CIN) * HS * WS;

    // acc[r1*2+r2]: pixel A = (h,w), pixel B = (h,w+1)
    float a00 = sb4[0], a01 = sb4[1], a10 = sb4[2], a11 = sb4[3];
    float b00 = sb4[0], b01 = sb4[1], b10 = sb4[2], b11 = sb4[3];

    #pragma unroll
    for (int ic = 0; ic < CIN; ++ic) {
        const float* __restrict__ xp = xb + ic * HS * WS;
        #pragma unroll
        for (int ky = 0; ky < 3; ++ky) {
            const int iy   = h + ky - 1;
            const bool yok = (unsigned)iy < (unsigned)HS;  // wave-uniform branch
            float pm = 0.0f, pc0 = 0.0f, pc1 = 0.0f, pp = 0.0f;
            if (yok) {
                const float* __restrict__ row = xp + iy * WS + w;
                const float2 pc = *(const float2*)row;     // x[w], x[w+1] (8B aligned)
                pc0 = pc.x; pc1 = pc.y;
                pm = (w2 > 0)  ? row[-1] : 0.0f;
                pp = (w2 < 63) ? row[2]  : 0.0f;
            }
            const float* __restrict__ wp = sw + ic * 9 + ky * 3;  // + oc4*27
            // pixel A patch row [pm, pc0, pc1]; pixel B patch row [pc0, pc1, pp]
            a00 = fmaf(pm,  wp[0],  fmaf(pc0, wp[1],  fmaf(pc1, wp[2],  a00)));
            a01 = fmaf(pm,  wp[27], fmaf(pc0, wp[28], fmaf(pc1, wp[29], a01)));
            a10 = fmaf(pm,  wp[54], fmaf(pc0, wp[55], fmaf(pc1, wp[56], a10)));
            a11 = fmaf(pm,  wp[81], fmaf(pc0, wp[82], fmaf(pc1, wp[83], a11)));
            b00 = fmaf(pc0, wp[0],  fmaf(pc1, wp[1],  fmaf(pp,  wp[2],  b00)));
            b01 = fmaf(pc0, wp[27], fmaf(pc1, wp[28], fmaf(pp,  wp[29], b01)));
            b10 = fmaf(pc0, wp[54], fmaf(pc1, wp[55], fmaf(pp,  wp[56], b10)));
            b11 = fmaf(pc0, wp[81], fmaf(pc1, wp[82], fmaf(pp,  wp[83], b11)));
        }
    }

    // out rows y0/y0+1, cols 4*w2 .. 4*w2+3: [A00 A01 B00 B01] / [A10 A11 B10 B11]
    const int y0 = 2 * h;
    float* __restrict__ ob =
        out + (((size_t)(b * CIN + c) * H2) + y0) * W2 + 4 * w2;
    float4 r0 = make_float4(a00 + sob, a01 + sob, b00 + sob, b01 + sob);
    float4 r1 = make_float4(a10 + sob, a11 + sob, b10 + sob, b11 + sob);
    *(float4*)ob        = r0;
    *(float4*)(ob + W2) = r1;
}

extern "C" void kernel_launch(void* const* d_in, const int* in_sizes, int n_in,
                              void* d_out, int out_size, void* d_ws, size_t ws_size,
                              hipStream_t stream) {
    // setup_inputs order: x, up_w, up_b, in_w, in_b, adder_w, out_w, out_b
    const float* x     = (const float*)d_in[0];
    const float* up_w  = (const float*)d_in[1];
    const float* up_b  = (const float*)d_in[2];
    const float* out_b = (const float*)d_in[7];
    float* out = (float*)d_out;

    const int blocks = BATCH * CIN * (HS * (WS / 2)) / 256;  // 192
    upshuffle4x2_kernel<<<blocks, 256, 0, stream>>>(x, up_w, up_b, out_b, out);
}